// Round 9
// baseline (236.967 us; speedup 1.0000x reference)
//
#include <hip/hip_runtime.h>

typedef __attribute__((ext_vector_type(8))) short short8;
typedef __attribute__((ext_vector_type(4))) float f32x4;
typedef __attribute__((ext_vector_type(4))) unsigned int u32x4;

#define C_DIM 2048
#define KW 256
#define HW_DIM 4096

__device__ __forceinline__ short f2bf(float f) {
    unsigned u = __builtin_bit_cast(unsigned, f);
    unsigned r = (u + 0x7fffu + ((u >> 16) & 1u)) >> 16;
    return (short)r;
}

// ---------- Kernel 1: normalize centroid -> bf16 w_norm in k2's FRAGMENT layout ----------
// wt layout: [cc(32)][ks(2)][g(4)][k(256)][c8(8)], c = cc*64 + ks*32 + g*8 + c8.
__global__ __launch_bounds__(256) void k1_prep(const float* __restrict__ centroid,
                                               short* __restrict__ wt,
                                               float* __restrict__ xhist,
                                               int* __restrict__ counts,
                                               float4* __restrict__ partialz) {
    const int row = blockIdx.x, t = threadIdx.x;
    const float* src = centroid + row * C_DIM;
    float v[8]; float ss = 0.f;
#pragma unroll
    for (int i = 0; i < 8; ++i) { v[i] = src[t + 256 * i]; ss += v[i] * v[i]; }
#pragma unroll
    for (int off = 1; off < 64; off <<= 1) ss += __shfl_xor(ss, off);
    __shared__ float red[4];
    if ((t & 63) == 0) red[t >> 6] = ss;
    __syncthreads();
    const float tot = red[0] + red[1] + red[2] + red[3];
    const float inv = 1.0f / fmaxf(sqrtf(tot), 1e-12f);
#pragma unroll
    for (int i = 0; i < 8; ++i) {
        const int c = t + 256 * i;
        const int idx = ((((c >> 6) * 2 + ((c >> 5) & 1)) * 4 + ((c >> 3) & 3)) * 256 + row) * 8 + (c & 7);
        wt[idx] = f2bf(v[i] * inv);
    }
    if (row == 0) {
        for (int i = t; i < 2048; i += 256) { xhist[i] = 0.f; counts[i] = 0; }
    }
    const int gid = blockIdx.x * 256 + t;
    const float4 z = {0.f, 0.f, 0.f, 0.f};
#pragma unroll
    for (int i = 0; i < 16; ++i) partialz[gid + 65536 * i] = z;
}

// ---------- Kernel 2: fused GEMM, 2-phase software pipeline (raw s_barrier + counted waitcnt) ----------
__global__ __launch_bounds__(256, 2) void k2_main(const float* __restrict__ x,
                                                  const short* __restrict__ wt,
                                                  float* __restrict__ xcorr,
                                                  float* __restrict__ xhist,
                                                  int* __restrict__ labels,
                                                  int* __restrict__ counts) {
    __shared__ float sf[2][64 * 64];     // double-buffered f32 staging tile [c:64][n:64]
    __shared__ short bfr[8 * 64 * 8];    // bf16 frag tile [unit:8][n:64][8c]
    __shared__ float ssred[4][64];
    __shared__ float invn[64];
    __shared__ float wmax[4][64];
    __shared__ int   warg[4][64];
    __shared__ float wred[4][64];
    __shared__ float Sn[64];

    const int t = threadIdx.x;
    const int w = t >> 6, l = t & 63;
    const int p = l & 15, g = l >> 4;
    const int n0 = blockIdx.x * 64;
    const int b = n0 >> 12, hw0 = n0 & 4095;
    const float* xb = x + (size_t)b * C_DIM * HW_DIM + hw0;

    f32x4 acc[4][4];
#pragma unroll
    for (int i = 0; i < 4; ++i)
#pragma unroll
        for (int j = 0; j < 4; ++j) acc[i][j] = (f32x4)0.f;

    float ss = 0.f;
    int cur = 0;

#pragma unroll
    for (int q = 0; q < 4; ++q) {
        const int row = 4 * w + 16 * q + (l >> 4);
        const float* gsrc = xb + (size_t)row * HW_DIM + (l & 15) * 4;
        float* ldst = &sf[0][(4 * w + 16 * q) * 64];
        __builtin_amdgcn_global_load_lds(
            (const __attribute__((address_space(1))) unsigned int*)gsrc,
            (__attribute__((address_space(3))) unsigned int*)ldst, 16, 0, 0);
    }
    asm volatile("s_waitcnt vmcnt(0)" ::: "memory");
    __syncthreads();

#pragma unroll 1
    for (int cc = 0; cc < 32; ++cc) {
        const int cb = cc * 64;
        short8 af[2][4];
#pragma unroll
        for (int ks = 0; ks < 2; ++ks)
#pragma unroll
            for (int mf = 0; mf < 4; ++mf)
                af[ks][mf] = *(const short8*)(wt + (((size_t)(cc * 2 + ks) * 4 + g) * 256 + (w * 64 + mf * 16 + p)) * 8);
        __builtin_amdgcn_sched_barrier(0);
        if (cc + 1 < 32) {
#pragma unroll
            for (int q = 0; q < 4; ++q) {
                const int row = 4 * w + 16 * q + (l >> 4);
                const float* gsrc = xb + (size_t)(cb + 64 + row) * HW_DIM + (l & 15) * 4;
                float* ldst = &sf[cur ^ 1][(4 * w + 16 * q) * 64];
                __builtin_amdgcn_global_load_lds(
                    (const __attribute__((address_space(1))) unsigned int*)gsrc,
                    (__attribute__((address_space(3))) unsigned int*)ldst, 16, 0, 0);
            }
        }
        __builtin_amdgcn_sched_barrier(0);
        float tv[16];
#pragma unroll
        for (int j = 0; j < 16; ++j) {
            tv[j] = sf[cur][(16 * w + j) * 64 + l];
            ss += tv[j] * tv[j];
        }
        short8 pk0, pk1;
#pragma unroll
        for (int j = 0; j < 8; ++j) { pk0[j] = f2bf(tv[j]); pk1[j] = f2bf(tv[8 + j]); }
        *(short8*)(&bfr[((2 * w + 0) * 64 + l) * 8]) = pk0;
        *(short8*)(&bfr[((2 * w + 1) * 64 + l) * 8]) = pk1;
        asm volatile("s_waitcnt lgkmcnt(0)" ::: "memory");
        __builtin_amdgcn_sched_barrier(0);
        __builtin_amdgcn_s_barrier();
#pragma unroll
        for (int ks = 0; ks < 2; ++ks) {
            short8 bf[4];
#pragma unroll
            for (int nf = 0; nf < 4; ++nf)
                bf[nf] = *(const short8*)(&bfr[((ks * 4 + g) * 64 + nf * 16 + p) * 8]);
#pragma unroll
            for (int mf = 0; mf < 4; ++mf)
#pragma unroll
                for (int nf = 0; nf < 4; ++nf)
                    acc[mf][nf] = __builtin_amdgcn_mfma_f32_16x16x32_bf16(
                        af[ks][mf], bf[nf], acc[mf][nf], 0, 0, 0);
        }
        asm volatile("s_waitcnt vmcnt(0)" ::: "memory");
        __builtin_amdgcn_sched_barrier(0);
        __builtin_amdgcn_s_barrier();
        cur ^= 1;
    }

    // ---- epilogue: pixel norms ----
    ssred[w][l] = ss;
    __syncthreads();
    if (t < 64) {
        const float s = ssred[0][t] + ssred[1][t] + ssred[2][t] + ssred[3][t];
        invn[t] = 1.0f / fmaxf(sqrtf(s), 1e-12f);
    }
    __syncthreads();
    float inv[4];
#pragma unroll
    for (int nf = 0; nf < 4; ++nf) inv[nf] = invn[nf * 16 + p];

    float mx[4]; int ai[4];
#pragma unroll
    for (int nf = 0; nf < 4; ++nf) { mx[nf] = -3.0e38f; ai[nf] = 0; }
#pragma unroll
    for (int mf = 0; mf < 4; ++mf)
#pragma unroll
        for (int r = 0; r < 4; ++r) {
            const int k = w * 64 + mf * 16 + g * 4 + r;
#pragma unroll
            for (int nf = 0; nf < 4; ++nf) {
                const float v = acc[mf][nf][r] * inv[nf];
                if (v > mx[nf]) { mx[nf] = v; ai[nf] = k; }
            }
        }
#pragma unroll
    for (int off = 16; off <= 32; off <<= 1)
#pragma unroll
        for (int nf = 0; nf < 4; ++nf) {
            const float ov = __shfl_xor(mx[nf], off);
            const int   oi = __shfl_xor(ai[nf], off);
            if (ov > mx[nf] || (ov == mx[nf] && oi < ai[nf])) { mx[nf] = ov; ai[nf] = oi; }
        }
    if (l < 16) {
#pragma unroll
        for (int nf = 0; nf < 4; ++nf) { wmax[w][nf * 16 + l] = mx[nf]; warg[w][nf * 16 + l] = ai[nf]; }
    }
    __syncthreads();
    if (t < 64) {
        float m = wmax[0][t]; int a = warg[0][t];
#pragma unroll
        for (int ww = 1; ww < 4; ++ww) {
            const float om = wmax[ww][t]; const int oa = warg[ww][t];
            if (om > m || (om == m && oa < a)) { m = om; a = oa; }
        }
        labels[n0 + t] = a;
        atomicAdd(&counts[b * KW + a], 1);
    }

    float se[4] = {0.f, 0.f, 0.f, 0.f};
#pragma unroll
    for (int mf = 0; mf < 4; ++mf)
#pragma unroll
        for (int r = 0; r < 4; ++r)
#pragma unroll
            for (int nf = 0; nf < 4; ++nf)
                se[nf] += __expf(acc[mf][nf][r] * inv[nf]);
#pragma unroll
    for (int off = 16; off <= 32; off <<= 1)
#pragma unroll
        for (int nf = 0; nf < 4; ++nf) se[nf] += __shfl_xor(se[nf], off);
    if (l < 16) {
#pragma unroll
        for (int nf = 0; nf < 4; ++nf) wred[w][nf * 16 + l] = se[nf];
    }
    __syncthreads();
    if (t < 64) Sn[t] = wred[0][t] + wred[1][t] + wred[2][t] + wred[3][t];
    __syncthreads();

    float rs[4];
#pragma unroll
    for (int nf = 0; nf < 4; ++nf) rs[nf] = 1.0f / Sn[nf * 16 + p];

    float hist[4][4];
#pragma unroll
    for (int mf = 0; mf < 4; ++mf)
#pragma unroll
        for (int r = 0; r < 4; ++r) hist[mf][r] = 0.f;
#pragma unroll
    for (int mf = 0; mf < 4; ++mf)
#pragma unroll
        for (int r = 0; r < 4; ++r) {
            const int k = w * 64 + mf * 16 + g * 4 + r;
            float* orow = xcorr + ((size_t)(b * KW + k) << 12) + hw0;
#pragma unroll
            for (int nf = 0; nf < 4; ++nf) {
                const float pr = __expf(acc[mf][nf][r] * inv[nf]) * rs[nf];
                orow[nf * 16 + p] = pr;
                hist[mf][r] += pr;
            }
        }
#pragma unroll
    for (int off = 1; off <= 8; off <<= 1)
#pragma unroll
        for (int mf = 0; mf < 4; ++mf)
#pragma unroll
            for (int r = 0; r < 4; ++r) hist[mf][r] += __shfl_xor(hist[mf][r], off);
    if (p == 0) {
#pragma unroll
        for (int mf = 0; mf < 4; ++mf)
#pragma unroll
            for (int r = 0; r < 4; ++r)
                unsafeAtomicAdd(&xhist[b * KW + w * 64 + mf * 16 + g * 4 + r], hist[mf][r]);
    }
}

// ---------- Kernel 3: MFMA segmented-sum, k SPLIT OVER WAVES ----------
// grid 2048 = 8 b x 4 px-groups(1024px) x 64 c-chunks(32c). Block: 32 c x 256 k x 1024 px.
// Wave w owns k in [64w, 64w+64) (4 mf-groups); all waves share the same B (x) data.
// A-expansion per wave: only 4 mf shifts of the 16-bit one-hot encoding.
__global__ __launch_bounds__(256, 4) void k3_ctr(const float* __restrict__ x,
                                                 const int* __restrict__ labels,
                                                 float* __restrict__ partial) {
    __shared__ int lab[1024];
    const int t = threadIdx.x;
    const int w = t >> 6, l = t & 63;
    const int p = l & 15, g = l >> 4;
    const int cc = blockIdx.x & 63;
    const int pg = (blockIdx.x >> 6) & 3;
    const int b  = blockIdx.x >> 8;
    ((int4*)lab)[t] = ((const int4*)(labels + b * HW_DIM + pg * 1024))[t];
    __syncthreads();

    const int c0 = cc * 32 + p;
    const int c1 = c0 + 16;
    const float* xr0 = x + ((size_t)b * C_DIM + c0) * HW_DIM + pg * 1024;
    const float* xr1 = x + ((size_t)b * C_DIM + c1) * HW_DIM + pg * 1024;

    f32x4 accA[4], accB[4];   // [mfl] for chunk0 / chunk1
#pragma unroll
    for (int mfl = 0; mfl < 4; ++mfl) { accA[mfl] = (f32x4)0.f; accB[mfl] = (f32x4)0.f; }

    float4 a0 = *(const float4*)(xr0 + g * 8);
    float4 a1 = *(const float4*)(xr0 + g * 8 + 4);
    float4 e0 = *(const float4*)(xr1 + g * 8);
    float4 e1 = *(const float4*)(xr1 + g * 8 + 4);

#pragma unroll 1
    for (int px0 = 0; px0 < 1024; px0 += 32) {
        const int4 L0 = *(const int4*)(&lab[px0 + g * 8]);
        const int4 L1 = *(const int4*)(&lab[px0 + g * 8 + 4]);
        const int pxn = (px0 + 32 < 1024) ? (px0 + 32) : px0;
        float4 na0 = *(const float4*)(xr0 + pxn + g * 8);
        float4 na1 = *(const float4*)(xr0 + pxn + g * 8 + 4);
        float4 ne0 = *(const float4*)(xr1 + pxn + g * 8);
        float4 ne1 = *(const float4*)(xr1 + pxn + g * 8 + 4);

        short8 bfA, bfB;
        bfA[0] = f2bf(a0.x); bfA[1] = f2bf(a0.y); bfA[2] = f2bf(a0.z); bfA[3] = f2bf(a0.w);
        bfA[4] = f2bf(a1.x); bfA[5] = f2bf(a1.y); bfA[6] = f2bf(a1.z); bfA[7] = f2bf(a1.w);
        bfB[0] = f2bf(e0.x); bfB[1] = f2bf(e0.y); bfB[2] = f2bf(e0.z); bfB[3] = f2bf(e0.w);
        bfB[4] = f2bf(e1.x); bfB[5] = f2bf(e1.y); bfB[6] = f2bf(e1.z); bfB[7] = f2bf(e1.w);

        // 16-bit one-hot encoding: bits_j bit m set iff lab == m*16 + p
        const int lj[8] = {L0.x, L0.y, L0.z, L0.w, L1.x, L1.y, L1.z, L1.w};
        unsigned bits[8];
#pragma unroll
        for (int j = 0; j < 8; ++j)
            bits[j] = ((lj[j] & 15) == p) ? (1u << (lj[j] >> 4)) : 0u;
        const unsigned cmb0 = bits[0] | (bits[1] << 16);
        const unsigned cmb1 = bits[2] | (bits[3] << 16);
        const unsigned cmb2 = bits[4] | (bits[5] << 16);
        const unsigned cmb3 = bits[6] | (bits[7] << 16);

#pragma unroll
        for (int mfl = 0; mfl < 4; ++mfl) {
            const int sh = 4 * w + mfl;
            u32x4 ar;
            ar[0] = ((cmb0 >> sh) & 0x00010001u) * 0x3F80u;
            ar[1] = ((cmb1 >> sh) & 0x00010001u) * 0x3F80u;
            ar[2] = ((cmb2 >> sh) & 0x00010001u) * 0x3F80u;
            ar[3] = ((cmb3 >> sh) & 0x00010001u) * 0x3F80u;
            const short8 af = __builtin_bit_cast(short8, ar);
            accA[mfl] = __builtin_amdgcn_mfma_f32_16x16x32_bf16(af, bfA, accA[mfl], 0, 0, 0);
            accB[mfl] = __builtin_amdgcn_mfma_f32_16x16x32_bf16(af, bfB, accB[mfl], 0, 0, 0);
        }
        a0 = na0; a1 = na1; e0 = ne0; e1 = ne1;
    }

    // flush: rows k = (4w+mfl)*16 + g*4 + r, cols c0/c1 (4 pg blocks collide per address)
#pragma unroll
    for (int mfl = 0; mfl < 4; ++mfl)
#pragma unroll
        for (int r = 0; r < 4; ++r) {
            const size_t rowoff = (size_t)(b * KW + (4 * w + mfl) * 16 + g * 4 + r) << 11;
            unsafeAtomicAdd(&partial[rowoff + c0], accA[mfl][r]);
            unsafeAtomicAdd(&partial[rowoff + c1], accB[mfl][r]);
        }
}

// ---------- Kernel 4: reduce partials, EMA update, y_word ----------
__global__ __launch_bounds__(256) void k4_final(const float* __restrict__ partial,
                                                const int* __restrict__ counts,
                                                const float* __restrict__ centroid,
                                                float* __restrict__ out_c,
                                                float* __restrict__ y_word) {
    const int idx = blockIdx.x * 256 + threadIdx.x;
    const int k = idx >> 11, c = idx & 2047;
    float s = 0.f;
#pragma unroll
    for (int pi = 0; pi < 8; ++pi) s += partial[((size_t)(pi * KW + k) << 11) + c];
    int cnt = 0;
#pragma unroll
    for (int bb = 0; bb < 8; ++bb) cnt += counts[bb * KW + k];
    const float ctr = s / ((float)cnt + 1e-4f);
    out_c[idx] = 0.01f * ctr + 0.99f * centroid[idx];
    if (idx < 2048) y_word[idx] = (counts[idx] > 0) ? 1.0f : 0.0f;
}

extern "C" void kernel_launch(void* const* d_in, const int* in_sizes, int n_in,
                              void* d_out, int out_size, void* d_ws, size_t ws_size,
                              hipStream_t stream) {
    const float* x        = (const float*)d_in[0];
    const float* centroid = (const float*)d_in[1];
    float* out   = (float*)d_out;
    float* xcorr = out;                 // 8*256*4096
    float* xhist = out + 8388608;       // 2048
    float* yword = out + 8390656;       // 2048
    float* outc  = out + 8392704;       // 256*2048

    char* ws = (char*)d_ws;
    short* wt      = (short*)ws;                                    // 1 MiB (fragment layout)
    int*   labels  = (int*)(ws + (1 << 20));                        // 128 KiB
    int*   counts  = (int*)(ws + (1 << 20) + 131072);               // 8 KiB
    float* partial = (float*)(ws + (1 << 20) + 131072 + 8192);      // 16 MiB

    hipLaunchKernelGGL(k1_prep,  dim3(256),  dim3(256), 0, stream, centroid, wt, xhist, counts, (float4*)partial);
    hipLaunchKernelGGL(k2_main,  dim3(512),  dim3(256), 0, stream, x, wt, xcorr, xhist, labels, counts);
    hipLaunchKernelGGL(k3_ctr,   dim3(2048), dim3(256), 0, stream, x, labels, partial);
    hipLaunchKernelGGL(k4_final, dim3(2048), dim3(256), 0, stream, partial, counts, centroid, outc, yword);
}

// Round 10
// 171.177 us; speedup vs baseline: 1.3843x; 1.3843x over previous
//
#include <hip/hip_runtime.h>

typedef __attribute__((ext_vector_type(8))) short short8;
typedef __attribute__((ext_vector_type(4))) float f32x4;
typedef __attribute__((ext_vector_type(4))) unsigned int u32x4;

#define C_DIM 2048
#define KW 256
#define HW_DIM 4096

__device__ __forceinline__ short f2bf(float f) {
    unsigned u = __builtin_bit_cast(unsigned, f);
    unsigned r = (u + 0x7fffu + ((u >> 16) & 1u)) >> 16;
    return (short)r;
}

// ---------- Kernel 1: normalize centroid -> bf16 w_norm in k2's FRAGMENT layout ----------
__global__ __launch_bounds__(256) void k1_prep(const float* __restrict__ centroid,
                                               short* __restrict__ wt,
                                               float* __restrict__ xhist,
                                               int* __restrict__ counts,
                                               float4* __restrict__ partialz) {
    const int row = blockIdx.x, t = threadIdx.x;
    const float* src = centroid + row * C_DIM;
    float v[8]; float ss = 0.f;
#pragma unroll
    for (int i = 0; i < 8; ++i) { v[i] = src[t + 256 * i]; ss += v[i] * v[i]; }
#pragma unroll
    for (int off = 1; off < 64; off <<= 1) ss += __shfl_xor(ss, off);
    __shared__ float red[4];
    if ((t & 63) == 0) red[t >> 6] = ss;
    __syncthreads();
    const float tot = red[0] + red[1] + red[2] + red[3];
    const float inv = 1.0f / fmaxf(sqrtf(tot), 1e-12f);
#pragma unroll
    for (int i = 0; i < 8; ++i) {
        const int c = t + 256 * i;
        const int idx = ((((c >> 6) * 2 + ((c >> 5) & 1)) * 4 + ((c >> 3) & 3)) * 256 + row) * 8 + (c & 7);
        wt[idx] = f2bf(v[i] * inv);
    }
    if (row == 0) {
        for (int i = t; i < 2048; i += 256) { xhist[i] = 0.f; counts[i] = 0; }
    }
    const int gid = blockIdx.x * 256 + t;
    const float4 z = {0.f, 0.f, 0.f, 0.f};
#pragma unroll
    for (int i = 0; i < 16; ++i) partialz[gid + 65536 * i] = z;
}

// ---------- Kernel 2: fused GEMM, 2-phase software pipeline (raw s_barrier + counted waitcnt) ----------
__global__ __launch_bounds__(256, 2) void k2_main(const float* __restrict__ x,
                                                  const short* __restrict__ wt,
                                                  float* __restrict__ xcorr,
                                                  float* __restrict__ xhist,
                                                  int* __restrict__ labels,
                                                  int* __restrict__ counts) {
    __shared__ float sf[2][64 * 64];
    __shared__ short bfr[8 * 64 * 8];
    __shared__ float ssred[4][64];
    __shared__ float invn[64];
    __shared__ float wmax[4][64];
    __shared__ int   warg[4][64];
    __shared__ float wred[4][64];
    __shared__ float Sn[64];

    const int t = threadIdx.x;
    const int w = t >> 6, l = t & 63;
    const int p = l & 15, g = l >> 4;
    const int n0 = blockIdx.x * 64;
    const int b = n0 >> 12, hw0 = n0 & 4095;
    const float* xb = x + (size_t)b * C_DIM * HW_DIM + hw0;

    f32x4 acc[4][4];
#pragma unroll
    for (int i = 0; i < 4; ++i)
#pragma unroll
        for (int j = 0; j < 4; ++j) acc[i][j] = (f32x4)0.f;

    float ss = 0.f;
    int cur = 0;

#pragma unroll
    for (int q = 0; q < 4; ++q) {
        const int row = 4 * w + 16 * q + (l >> 4);
        const float* gsrc = xb + (size_t)row * HW_DIM + (l & 15) * 4;
        float* ldst = &sf[0][(4 * w + 16 * q) * 64];
        __builtin_amdgcn_global_load_lds(
            (const __attribute__((address_space(1))) unsigned int*)gsrc,
            (__attribute__((address_space(3))) unsigned int*)ldst, 16, 0, 0);
    }
    asm volatile("s_waitcnt vmcnt(0)" ::: "memory");
    __syncthreads();

#pragma unroll 1
    for (int cc = 0; cc < 32; ++cc) {
        const int cb = cc * 64;
        short8 af[2][4];
#pragma unroll
        for (int ks = 0; ks < 2; ++ks)
#pragma unroll
            for (int mf = 0; mf < 4; ++mf)
                af[ks][mf] = *(const short8*)(wt + (((size_t)(cc * 2 + ks) * 4 + g) * 256 + (w * 64 + mf * 16 + p)) * 8);
        __builtin_amdgcn_sched_barrier(0);
        if (cc + 1 < 32) {
#pragma unroll
            for (int q = 0; q < 4; ++q) {
                const int row = 4 * w + 16 * q + (l >> 4);
                const float* gsrc = xb + (size_t)(cb + 64 + row) * HW_DIM + (l & 15) * 4;
                float* ldst = &sf[cur ^ 1][(4 * w + 16 * q) * 64];
                __builtin_amdgcn_global_load_lds(
                    (const __attribute__((address_space(1))) unsigned int*)gsrc,
                    (__attribute__((address_space(3))) unsigned int*)ldst, 16, 0, 0);
            }
        }
        __builtin_amdgcn_sched_barrier(0);
        float tv[16];
#pragma unroll
        for (int j = 0; j < 16; ++j) {
            tv[j] = sf[cur][(16 * w + j) * 64 + l];
            ss += tv[j] * tv[j];
        }
        short8 pk0, pk1;
#pragma unroll
        for (int j = 0; j < 8; ++j) { pk0[j] = f2bf(tv[j]); pk1[j] = f2bf(tv[8 + j]); }
        *(short8*)(&bfr[((2 * w + 0) * 64 + l) * 8]) = pk0;
        *(short8*)(&bfr[((2 * w + 1) * 64 + l) * 8]) = pk1;
        asm volatile("s_waitcnt lgkmcnt(0)" ::: "memory");
        __builtin_amdgcn_sched_barrier(0);
        __builtin_amdgcn_s_barrier();
#pragma unroll
        for (int ks = 0; ks < 2; ++ks) {
            short8 bf[4];
#pragma unroll
            for (int nf = 0; nf < 4; ++nf)
                bf[nf] = *(const short8*)(&bfr[((ks * 4 + g) * 64 + nf * 16 + p) * 8]);
#pragma unroll
            for (int mf = 0; mf < 4; ++mf)
#pragma unroll
                for (int nf = 0; nf < 4; ++nf)
                    acc[mf][nf] = __builtin_amdgcn_mfma_f32_16x16x32_bf16(
                        af[ks][mf], bf[nf], acc[mf][nf], 0, 0, 0);
        }
        asm volatile("s_waitcnt vmcnt(0)" ::: "memory");
        __builtin_amdgcn_sched_barrier(0);
        __builtin_amdgcn_s_barrier();
        cur ^= 1;
    }

    // ---- epilogue ----
    ssred[w][l] = ss;
    __syncthreads();
    if (t < 64) {
        const float s = ssred[0][t] + ssred[1][t] + ssred[2][t] + ssred[3][t];
        invn[t] = 1.0f / fmaxf(sqrtf(s), 1e-12f);
    }
    __syncthreads();
    float inv[4];
#pragma unroll
    for (int nf = 0; nf < 4; ++nf) inv[nf] = invn[nf * 16 + p];

    float mx[4]; int ai[4];
#pragma unroll
    for (int nf = 0; nf < 4; ++nf) { mx[nf] = -3.0e38f; ai[nf] = 0; }
#pragma unroll
    for (int mf = 0; mf < 4; ++mf)
#pragma unroll
        for (int r = 0; r < 4; ++r) {
            const int k = w * 64 + mf * 16 + g * 4 + r;
#pragma unroll
            for (int nf = 0; nf < 4; ++nf) {
                const float v = acc[mf][nf][r] * inv[nf];
                if (v > mx[nf]) { mx[nf] = v; ai[nf] = k; }
            }
        }
#pragma unroll
    for (int off = 16; off <= 32; off <<= 1)
#pragma unroll
        for (int nf = 0; nf < 4; ++nf) {
            const float ov = __shfl_xor(mx[nf], off);
            const int   oi = __shfl_xor(ai[nf], off);
            if (ov > mx[nf] || (ov == mx[nf] && oi < ai[nf])) { mx[nf] = ov; ai[nf] = oi; }
        }
    if (l < 16) {
#pragma unroll
        for (int nf = 0; nf < 4; ++nf) { wmax[w][nf * 16 + l] = mx[nf]; warg[w][nf * 16 + l] = ai[nf]; }
    }
    __syncthreads();
    if (t < 64) {
        float m = wmax[0][t]; int a = warg[0][t];
#pragma unroll
        for (int ww = 1; ww < 4; ++ww) {
            const float om = wmax[ww][t]; const int oa = warg[ww][t];
            if (om > m || (om == m && oa < a)) { m = om; a = oa; }
        }
        labels[n0 + t] = a;
        atomicAdd(&counts[b * KW + a], 1);
    }

    float se[4] = {0.f, 0.f, 0.f, 0.f};
#pragma unroll
    for (int mf = 0; mf < 4; ++mf)
#pragma unroll
        for (int r = 0; r < 4; ++r)
#pragma unroll
            for (int nf = 0; nf < 4; ++nf)
                se[nf] += __expf(acc[mf][nf][r] * inv[nf]);
#pragma unroll
    for (int off = 16; off <= 32; off <<= 1)
#pragma unroll
        for (int nf = 0; nf < 4; ++nf) se[nf] += __shfl_xor(se[nf], off);
    if (l < 16) {
#pragma unroll
        for (int nf = 0; nf < 4; ++nf) wred[w][nf * 16 + l] = se[nf];
    }
    __syncthreads();
    if (t < 64) Sn[t] = wred[0][t] + wred[1][t] + wred[2][t] + wred[3][t];
    __syncthreads();

    float rs[4];
#pragma unroll
    for (int nf = 0; nf < 4; ++nf) rs[nf] = 1.0f / Sn[nf * 16 + p];

    float hist[4][4];
#pragma unroll
    for (int mf = 0; mf < 4; ++mf)
#pragma unroll
        for (int r = 0; r < 4; ++r) hist[mf][r] = 0.f;
#pragma unroll
    for (int mf = 0; mf < 4; ++mf)
#pragma unroll
        for (int r = 0; r < 4; ++r) {
            const int k = w * 64 + mf * 16 + g * 4 + r;
            float* orow = xcorr + ((size_t)(b * KW + k) << 12) + hw0;
#pragma unroll
            for (int nf = 0; nf < 4; ++nf) {
                const float pr = __expf(acc[mf][nf][r] * inv[nf]) * rs[nf];
                orow[nf * 16 + p] = pr;
                hist[mf][r] += pr;
            }
        }
#pragma unroll
    for (int off = 1; off <= 8; off <<= 1)
#pragma unroll
        for (int mf = 0; mf < 4; ++mf)
#pragma unroll
            for (int r = 0; r < 4; ++r) hist[mf][r] += __shfl_xor(hist[mf][r], off);
    if (p == 0) {
#pragma unroll
        for (int mf = 0; mf < 4; ++mf)
#pragma unroll
            for (int r = 0; r < 4; ++r)
                unsafeAtomicAdd(&xhist[b * KW + w * 64 + mf * 16 + g * 4 + r], hist[mf][r]);
    }
}

// ---------- Kernel 3: MFMA segmented-sum (R8 structure) + 2-deep register prefetch ----------
// grid 512 = 8 b x 4 px-groups(1024px) x 16 cc(128c). Wave owns 32 c (c0, c0+16).
#define K3_BODY(A0, A1, E0, E1, PX, PF)                                          \
    {                                                                            \
        float4 nA0 = *(const float4*)(xr0 + (PF) + g * 8);                       \
        float4 nA1 = *(const float4*)(xr0 + (PF) + g * 8 + 4);                   \
        float4 nE0 = *(const float4*)(xr1 + (PF) + g * 8);                       \
        float4 nE1 = *(const float4*)(xr1 + (PF) + g * 8 + 4);                   \
        __builtin_amdgcn_sched_barrier(0);                                       \
        const int4 L0 = *(const int4*)(&lab[(PX) + g * 8]);                      \
        const int4 L1 = *(const int4*)(&lab[(PX) + g * 8 + 4]);                  \
        short8 bfA, bfB;                                                         \
        bfA[0] = f2bf(A0.x); bfA[1] = f2bf(A0.y); bfA[2] = f2bf(A0.z);           \
        bfA[3] = f2bf(A0.w); bfA[4] = f2bf(A1.x); bfA[5] = f2bf(A1.y);           \
        bfA[6] = f2bf(A1.z); bfA[7] = f2bf(A1.w);                                \
        bfB[0] = f2bf(E0.x); bfB[1] = f2bf(E0.y); bfB[2] = f2bf(E0.z);           \
        bfB[3] = f2bf(E0.w); bfB[4] = f2bf(E1.x); bfB[5] = f2bf(E1.y);           \
        bfB[6] = f2bf(E1.z); bfB[7] = f2bf(E1.w);                                \
        unsigned bits[8];                                                        \
        const int lj[8] = {L0.x, L0.y, L0.z, L0.w, L1.x, L1.y, L1.z, L1.w};      \
        _Pragma("unroll")                                                        \
        for (int j = 0; j < 8; ++j)                                              \
            bits[j] = ((lj[j] & 15) == p) ? (1u << (lj[j] >> 4)) : 0u;           \
        const unsigned cmb0 = bits[0] | (bits[1] << 16);                         \
        const unsigned cmb1 = bits[2] | (bits[3] << 16);                         \
        const unsigned cmb2 = bits[4] | (bits[5] << 16);                         \
        const unsigned cmb3 = bits[6] | (bits[7] << 16);                         \
        _Pragma("unroll")                                                        \
        for (int mf = 0; mf < 16; ++mf) {                                        \
            u32x4 ar;                                                            \
            ar[0] = ((cmb0 >> mf) & 0x00010001u) * 0x3F80u;                      \
            ar[1] = ((cmb1 >> mf) & 0x00010001u) * 0x3F80u;                      \
            ar[2] = ((cmb2 >> mf) & 0x00010001u) * 0x3F80u;                      \
            ar[3] = ((cmb3 >> mf) & 0x00010001u) * 0x3F80u;                      \
            const short8 af = __builtin_bit_cast(short8, ar);                    \
            accA[mf] = __builtin_amdgcn_mfma_f32_16x16x32_bf16(af, bfA, accA[mf], 0, 0, 0); \
            accB[mf] = __builtin_amdgcn_mfma_f32_16x16x32_bf16(af, bfB, accB[mf], 0, 0, 0); \
        }                                                                        \
        A0 = nA0; A1 = nA1; E0 = nE0; E1 = nE1;                                  \
    }

__global__ __launch_bounds__(256, 2) void k3_ctr(const float* __restrict__ x,
                                                 const int* __restrict__ labels,
                                                 float* __restrict__ partial) {
    __shared__ int lab[1024];
    const int t = threadIdx.x;
    const int w = t >> 6, l = t & 63;
    const int p = l & 15, g = l >> 4;
    const int cc = blockIdx.x & 15;
    const int pg = (blockIdx.x >> 4) & 3;
    const int b  = blockIdx.x >> 6;
    ((int4*)lab)[t] = ((const int4*)(labels + b * HW_DIM + pg * 1024))[t];
    __syncthreads();

    const int c0 = cc * 128 + w * 32 + p;
    const int c1 = c0 + 16;
    const float* xr0 = x + ((size_t)b * C_DIM + c0) * HW_DIM + pg * 1024;
    const float* xr1 = x + ((size_t)b * C_DIM + c1) * HW_DIM + pg * 1024;

    f32x4 accA[16], accB[16];
#pragma unroll
    for (int mf = 0; mf < 16; ++mf) { accA[mf] = (f32x4)0.f; accB[mf] = (f32x4)0.f; }

    // 2-deep prefetch: stage 0 = px0, stage 1 = px0+32
    float4 a0 = *(const float4*)(xr0 + g * 8);
    float4 a1 = *(const float4*)(xr0 + g * 8 + 4);
    float4 e0 = *(const float4*)(xr1 + g * 8);
    float4 e1 = *(const float4*)(xr1 + g * 8 + 4);
    float4 b0 = *(const float4*)(xr0 + 32 + g * 8);
    float4 b1 = *(const float4*)(xr0 + 32 + g * 8 + 4);
    float4 f0 = *(const float4*)(xr1 + 32 + g * 8);
    float4 f1 = *(const float4*)(xr1 + 32 + g * 8 + 4);

#pragma unroll 1
    for (int px0 = 0; px0 < 1024; px0 += 64) {
        const int pf1 = (px0 + 64 < 1024) ? px0 + 64 : px0;
        const int pf2 = (px0 + 96 < 1024) ? px0 + 96 : px0 + 32;
        K3_BODY(a0, a1, e0, e1, px0, pf1);
        K3_BODY(b0, b1, f0, f1, px0 + 32, pf2);
    }

#pragma unroll
    for (int mf = 0; mf < 16; ++mf)
#pragma unroll
        for (int r = 0; r < 4; ++r) {
            const size_t rowoff = (size_t)(b * KW + mf * 16 + g * 4 + r) << 11;
            unsafeAtomicAdd(&partial[rowoff + c0], accA[mf][r]);
            unsafeAtomicAdd(&partial[rowoff + c1], accB[mf][r]);
        }
}

// ---------- Kernel 4: reduce partials, EMA update, y_word ----------
__global__ __launch_bounds__(256) void k4_final(const float* __restrict__ partial,
                                                const int* __restrict__ counts,
                                                const float* __restrict__ centroid,
                                                float* __restrict__ out_c,
                                                float* __restrict__ y_word) {
    const int idx = blockIdx.x * 256 + threadIdx.x;
    const int k = idx >> 11, c = idx & 2047;
    float s = 0.f;
#pragma unroll
    for (int pi = 0; pi < 8; ++pi) s += partial[((size_t)(pi * KW + k) << 11) + c];
    int cnt = 0;
#pragma unroll
    for (int bb = 0; bb < 8; ++bb) cnt += counts[bb * KW + k];
    const float ctr = s / ((float)cnt + 1e-4f);
    out_c[idx] = 0.01f * ctr + 0.99f * centroid[idx];
    if (idx < 2048) y_word[idx] = (counts[idx] > 0) ? 1.0f : 0.0f;
}

extern "C" void kernel_launch(void* const* d_in, const int* in_sizes, int n_in,
                              void* d_out, int out_size, void* d_ws, size_t ws_size,
                              hipStream_t stream) {
    const float* x        = (const float*)d_in[0];
    const float* centroid = (const float*)d_in[1];
    float* out   = (float*)d_out;
    float* xcorr = out;                 // 8*256*4096
    float* xhist = out + 8388608;       // 2048
    float* yword = out + 8390656;       // 2048
    float* outc  = out + 8392704;       // 256*2048

    char* ws = (char*)d_ws;
    short* wt      = (short*)ws;                                    // 1 MiB (fragment layout)
    int*   labels  = (int*)(ws + (1 << 20));                        // 128 KiB
    int*   counts  = (int*)(ws + (1 << 20) + 131072);               // 8 KiB
    float* partial = (float*)(ws + (1 << 20) + 131072 + 8192);      // 16 MiB

    hipLaunchKernelGGL(k1_prep,  dim3(256),  dim3(256), 0, stream, centroid, wt, xhist, counts, (float4*)partial);
    hipLaunchKernelGGL(k2_main,  dim3(512),  dim3(256), 0, stream, x, wt, xcorr, xhist, labels, counts);
    hipLaunchKernelGGL(k3_ctr,   dim3(512),  dim3(256), 0, stream, x, labels, partial);
    hipLaunchKernelGGL(k4_final, dim3(2048), dim3(256), 0, stream, partial, counts, centroid, outc, yword);
}

// Round 11
// 154.850 us; speedup vs baseline: 1.5303x; 1.1054x over previous
//
#include <hip/hip_runtime.h>

typedef __attribute__((ext_vector_type(8))) short short8;
typedef __attribute__((ext_vector_type(4))) float f32x4;
typedef __attribute__((ext_vector_type(4))) unsigned int u32x4;

#define C_DIM 2048
#define KW 256
#define HW_DIM 4096

__device__ __forceinline__ short f2bf(float f) {
    unsigned u = __builtin_bit_cast(unsigned, f);
    unsigned r = (u + 0x7fffu + ((u >> 16) & 1u)) >> 16;
    return (short)r;
}

// ---------- Kernel 1: normalize centroid -> bf16 w_norm in k2's FRAGMENT layout ----------
// wt layout: [cc(32)][ks(2)][g(4)][k(256)][c8(8)], c = cc*64 + ks*32 + g*8 + c8.
__global__ __launch_bounds__(256) void k1_prep(const float* __restrict__ centroid,
                                               short* __restrict__ wt,
                                               float* __restrict__ xhist,
                                               int* __restrict__ counts) {
    const int row = blockIdx.x, t = threadIdx.x;
    const float* src = centroid + row * C_DIM;
    float v[8]; float ss = 0.f;
#pragma unroll
    for (int i = 0; i < 8; ++i) { v[i] = src[t + 256 * i]; ss += v[i] * v[i]; }
#pragma unroll
    for (int off = 1; off < 64; off <<= 1) ss += __shfl_xor(ss, off);
    __shared__ float red[4];
    if ((t & 63) == 0) red[t >> 6] = ss;
    __syncthreads();
    const float tot = red[0] + red[1] + red[2] + red[3];
    const float inv = 1.0f / fmaxf(sqrtf(tot), 1e-12f);
#pragma unroll
    for (int i = 0; i < 8; ++i) {
        const int c = t + 256 * i;
        const int idx = ((((c >> 6) * 2 + ((c >> 5) & 1)) * 4 + ((c >> 3) & 3)) * 256 + row) * 8 + (c & 7);
        wt[idx] = f2bf(v[i] * inv);
    }
    if (row == 0) {
        for (int i = t; i < 2048; i += 256) { xhist[i] = 0.f; counts[i] = 0; }
    }
}

// ---------- Kernel 2: fused GEMM, 2-phase software pipeline (raw s_barrier + counted waitcnt) ----------
__global__ __launch_bounds__(256, 2) void k2_main(const float* __restrict__ x,
                                                  const short* __restrict__ wt,
                                                  float* __restrict__ xcorr,
                                                  float* __restrict__ xhist,
                                                  int* __restrict__ labels,
                                                  int* __restrict__ counts) {
    __shared__ float sf[2][64 * 64];
    __shared__ short bfr[8 * 64 * 8];
    __shared__ float ssred[4][64];
    __shared__ float invn[64];
    __shared__ float wmax[4][64];
    __shared__ int   warg[4][64];
    __shared__ float wred[4][64];
    __shared__ float Sn[64];

    const int t = threadIdx.x;
    const int w = t >> 6, l = t & 63;
    const int p = l & 15, g = l >> 4;
    const int n0 = blockIdx.x * 64;
    const int b = n0 >> 12, hw0 = n0 & 4095;
    const float* xb = x + (size_t)b * C_DIM * HW_DIM + hw0;

    f32x4 acc[4][4];
#pragma unroll
    for (int i = 0; i < 4; ++i)
#pragma unroll
        for (int j = 0; j < 4; ++j) acc[i][j] = (f32x4)0.f;

    float ss = 0.f;
    int cur = 0;

#pragma unroll
    for (int q = 0; q < 4; ++q) {
        const int row = 4 * w + 16 * q + (l >> 4);
        const float* gsrc = xb + (size_t)row * HW_DIM + (l & 15) * 4;
        float* ldst = &sf[0][(4 * w + 16 * q) * 64];
        __builtin_amdgcn_global_load_lds(
            (const __attribute__((address_space(1))) unsigned int*)gsrc,
            (__attribute__((address_space(3))) unsigned int*)ldst, 16, 0, 0);
    }
    asm volatile("s_waitcnt vmcnt(0)" ::: "memory");
    __syncthreads();

#pragma unroll 1
    for (int cc = 0; cc < 32; ++cc) {
        const int cb = cc * 64;
        short8 af[2][4];
#pragma unroll
        for (int ks = 0; ks < 2; ++ks)
#pragma unroll
            for (int mf = 0; mf < 4; ++mf)
                af[ks][mf] = *(const short8*)(wt + (((size_t)(cc * 2 + ks) * 4 + g) * 256 + (w * 64 + mf * 16 + p)) * 8);
        __builtin_amdgcn_sched_barrier(0);
        if (cc + 1 < 32) {
#pragma unroll
            for (int q = 0; q < 4; ++q) {
                const int row = 4 * w + 16 * q + (l >> 4);
                const float* gsrc = xb + (size_t)(cb + 64 + row) * HW_DIM + (l & 15) * 4;
                float* ldst = &sf[cur ^ 1][(4 * w + 16 * q) * 64];
                __builtin_amdgcn_global_load_lds(
                    (const __attribute__((address_space(1))) unsigned int*)gsrc,
                    (__attribute__((address_space(3))) unsigned int*)ldst, 16, 0, 0);
            }
        }
        __builtin_amdgcn_sched_barrier(0);
        float tv[16];
#pragma unroll
        for (int j = 0; j < 16; ++j) {
            tv[j] = sf[cur][(16 * w + j) * 64 + l];
            ss += tv[j] * tv[j];
        }
        short8 pk0, pk1;
#pragma unroll
        for (int j = 0; j < 8; ++j) { pk0[j] = f2bf(tv[j]); pk1[j] = f2bf(tv[8 + j]); }
        *(short8*)(&bfr[((2 * w + 0) * 64 + l) * 8]) = pk0;
        *(short8*)(&bfr[((2 * w + 1) * 64 + l) * 8]) = pk1;
        asm volatile("s_waitcnt lgkmcnt(0)" ::: "memory");
        __builtin_amdgcn_sched_barrier(0);
        __builtin_amdgcn_s_barrier();
#pragma unroll
        for (int ks = 0; ks < 2; ++ks) {
            short8 bf[4];
#pragma unroll
            for (int nf = 0; nf < 4; ++nf)
                bf[nf] = *(const short8*)(&bfr[((ks * 4 + g) * 64 + nf * 16 + p) * 8]);
#pragma unroll
            for (int mf = 0; mf < 4; ++mf)
#pragma unroll
                for (int nf = 0; nf < 4; ++nf)
                    acc[mf][nf] = __builtin_amdgcn_mfma_f32_16x16x32_bf16(
                        af[ks][mf], bf[nf], acc[mf][nf], 0, 0, 0);
        }
        asm volatile("s_waitcnt vmcnt(0)" ::: "memory");
        __builtin_amdgcn_sched_barrier(0);
        __builtin_amdgcn_s_barrier();
        cur ^= 1;
    }

    // ---- epilogue ----
    ssred[w][l] = ss;
    __syncthreads();
    if (t < 64) {
        const float s = ssred[0][t] + ssred[1][t] + ssred[2][t] + ssred[3][t];
        invn[t] = 1.0f / fmaxf(sqrtf(s), 1e-12f);
    }
    __syncthreads();
    float inv[4];
#pragma unroll
    for (int nf = 0; nf < 4; ++nf) inv[nf] = invn[nf * 16 + p];

    float mx[4]; int ai[4];
#pragma unroll
    for (int nf = 0; nf < 4; ++nf) { mx[nf] = -3.0e38f; ai[nf] = 0; }
#pragma unroll
    for (int mf = 0; mf < 4; ++mf)
#pragma unroll
        for (int r = 0; r < 4; ++r) {
            const int k = w * 64 + mf * 16 + g * 4 + r;
#pragma unroll
            for (int nf = 0; nf < 4; ++nf) {
                const float v = acc[mf][nf][r] * inv[nf];
                if (v > mx[nf]) { mx[nf] = v; ai[nf] = k; }
            }
        }
#pragma unroll
    for (int off = 16; off <= 32; off <<= 1)
#pragma unroll
        for (int nf = 0; nf < 4; ++nf) {
            const float ov = __shfl_xor(mx[nf], off);
            const int   oi = __shfl_xor(ai[nf], off);
            if (ov > mx[nf] || (ov == mx[nf] && oi < ai[nf])) { mx[nf] = ov; ai[nf] = oi; }
        }
    if (l < 16) {
#pragma unroll
        for (int nf = 0; nf < 4; ++nf) { wmax[w][nf * 16 + l] = mx[nf]; warg[w][nf * 16 + l] = ai[nf]; }
    }
    __syncthreads();
    if (t < 64) {
        float m = wmax[0][t]; int a = warg[0][t];
#pragma unroll
        for (int ww = 1; ww < 4; ++ww) {
            const float om = wmax[ww][t]; const int oa = warg[ww][t];
            if (om > m || (om == m && oa < a)) { m = om; a = oa; }
        }
        labels[n0 + t] = a;
        atomicAdd(&counts[b * KW + a], 1);
    }

    float se[4] = {0.f, 0.f, 0.f, 0.f};
#pragma unroll
    for (int mf = 0; mf < 4; ++mf)
#pragma unroll
        for (int r = 0; r < 4; ++r)
#pragma unroll
            for (int nf = 0; nf < 4; ++nf)
                se[nf] += __expf(acc[mf][nf][r] * inv[nf]);
#pragma unroll
    for (int off = 16; off <= 32; off <<= 1)
#pragma unroll
        for (int nf = 0; nf < 4; ++nf) se[nf] += __shfl_xor(se[nf], off);
    if (l < 16) {
#pragma unroll
        for (int nf = 0; nf < 4; ++nf) wred[w][nf * 16 + l] = se[nf];
    }
    __syncthreads();
    if (t < 64) Sn[t] = wred[0][t] + wred[1][t] + wred[2][t] + wred[3][t];
    __syncthreads();

    float rs[4];
#pragma unroll
    for (int nf = 0; nf < 4; ++nf) rs[nf] = 1.0f / Sn[nf * 16 + p];

    float hist[4][4];
#pragma unroll
    for (int mf = 0; mf < 4; ++mf)
#pragma unroll
        for (int r = 0; r < 4; ++r) hist[mf][r] = 0.f;
#pragma unroll
    for (int mf = 0; mf < 4; ++mf)
#pragma unroll
        for (int r = 0; r < 4; ++r) {
            const int k = w * 64 + mf * 16 + g * 4 + r;
            float* orow = xcorr + ((size_t)(b * KW + k) << 12) + hw0;
#pragma unroll
            for (int nf = 0; nf < 4; ++nf) {
                const float pr = __expf(acc[mf][nf][r] * inv[nf]) * rs[nf];
                orow[nf * 16 + p] = pr;
                hist[mf][r] += pr;
            }
        }
#pragma unroll
    for (int off = 1; off <= 8; off <<= 1)
#pragma unroll
        for (int mf = 0; mf < 4; ++mf)
#pragma unroll
            for (int r = 0; r < 4; ++r) hist[mf][r] += __shfl_xor(hist[mf][r], off);
    if (p == 0) {
#pragma unroll
        for (int mf = 0; mf < 4; ++mf)
#pragma unroll
            for (int r = 0; r < 4; ++r)
                unsafeAtomicAdd(&xhist[b * KW + w * 64 + mf * 16 + g * 4 + r], hist[mf][r]);
    }
}

// ---------- Kernel 3: MFMA segmented-sum (R8 structure), ATOMIC-FREE flush ----------
// grid 512 = 8 b x 4 px-groups(1024px) x 16 cc(128c). Wave owns 32 c (c0, c0+16).
// Each (b,pg) writes its EXCLUSIVE 2 MB slice of partial4 with plain stores.
__global__ __launch_bounds__(256, 2) void k3_ctr(const float* __restrict__ x,
                                                 const int* __restrict__ labels,
                                                 float* __restrict__ partial4) {
    __shared__ int lab[1024];
    const int t = threadIdx.x;
    const int w = t >> 6, l = t & 63;
    const int p = l & 15, g = l >> 4;
    const int cc = blockIdx.x & 15;
    const int pg = (blockIdx.x >> 4) & 3;
    const int b  = blockIdx.x >> 6;
    ((int4*)lab)[t] = ((const int4*)(labels + b * HW_DIM + pg * 1024))[t];
    __syncthreads();

    const int c0 = cc * 128 + w * 32 + p;
    const int c1 = c0 + 16;
    const float* xr0 = x + ((size_t)b * C_DIM + c0) * HW_DIM + pg * 1024;
    const float* xr1 = x + ((size_t)b * C_DIM + c1) * HW_DIM + pg * 1024;

    f32x4 accA[16], accB[16];
#pragma unroll
    for (int mf = 0; mf < 16; ++mf) { accA[mf] = (f32x4)0.f; accB[mf] = (f32x4)0.f; }

    float4 a0 = *(const float4*)(xr0 + g * 8);
    float4 a1 = *(const float4*)(xr0 + g * 8 + 4);
    float4 e0 = *(const float4*)(xr1 + g * 8);
    float4 e1 = *(const float4*)(xr1 + g * 8 + 4);

#pragma unroll 1
    for (int px0 = 0; px0 < 1024; px0 += 32) {
        const int4 L0 = *(const int4*)(&lab[px0 + g * 8]);
        const int4 L1 = *(const int4*)(&lab[px0 + g * 8 + 4]);
        const int pxn = (px0 + 32 < 1024) ? (px0 + 32) : px0;
        float4 na0 = *(const float4*)(xr0 + pxn + g * 8);
        float4 na1 = *(const float4*)(xr0 + pxn + g * 8 + 4);
        float4 ne0 = *(const float4*)(xr1 + pxn + g * 8);
        float4 ne1 = *(const float4*)(xr1 + pxn + g * 8 + 4);

        short8 bfA, bfB;
        bfA[0] = f2bf(a0.x); bfA[1] = f2bf(a0.y); bfA[2] = f2bf(a0.z); bfA[3] = f2bf(a0.w);
        bfA[4] = f2bf(a1.x); bfA[5] = f2bf(a1.y); bfA[6] = f2bf(a1.z); bfA[7] = f2bf(a1.w);
        bfB[0] = f2bf(e0.x); bfB[1] = f2bf(e0.y); bfB[2] = f2bf(e0.z); bfB[3] = f2bf(e0.w);
        bfB[4] = f2bf(e1.x); bfB[5] = f2bf(e1.y); bfB[6] = f2bf(e1.z); bfB[7] = f2bf(e1.w);

        const int lj[8] = {L0.x, L0.y, L0.z, L0.w, L1.x, L1.y, L1.z, L1.w};
        unsigned bits[8];
#pragma unroll
        for (int j = 0; j < 8; ++j)
            bits[j] = ((lj[j] & 15) == p) ? (1u << (lj[j] >> 4)) : 0u;
        const unsigned cmb0 = bits[0] | (bits[1] << 16);
        const unsigned cmb1 = bits[2] | (bits[3] << 16);
        const unsigned cmb2 = bits[4] | (bits[5] << 16);
        const unsigned cmb3 = bits[6] | (bits[7] << 16);

#pragma unroll
        for (int mf = 0; mf < 16; ++mf) {
            u32x4 ar;
            ar[0] = ((cmb0 >> mf) & 0x00010001u) * 0x3F80u;
            ar[1] = ((cmb1 >> mf) & 0x00010001u) * 0x3F80u;
            ar[2] = ((cmb2 >> mf) & 0x00010001u) * 0x3F80u;
            ar[3] = ((cmb3 >> mf) & 0x00010001u) * 0x3F80u;
            const short8 af = __builtin_bit_cast(short8, ar);
            accA[mf] = __builtin_amdgcn_mfma_f32_16x16x32_bf16(af, bfA, accA[mf], 0, 0, 0);
            accB[mf] = __builtin_amdgcn_mfma_f32_16x16x32_bf16(af, bfB, accB[mf], 0, 0, 0);
        }
        a0 = na0; a1 = na1; e0 = ne0; e1 = ne1;
    }

    // flush: plain coalesced stores into this (b,pg)'s exclusive slice
    const int slice = b * 4 + pg;
#pragma unroll
    for (int mf = 0; mf < 16; ++mf)
#pragma unroll
        for (int r = 0; r < 4; ++r) {
            const size_t rowoff = (size_t)(slice * KW + mf * 16 + g * 4 + r) << 11;
            partial4[rowoff + c0] = accA[mf][r];
            partial4[rowoff + c1] = accB[mf][r];
        }
}

// ---------- Kernel 4: reduce 32 partial slices, EMA update, y_word ----------
__global__ __launch_bounds__(256) void k4_final(const float* __restrict__ partial4,
                                                const int* __restrict__ counts,
                                                const float* __restrict__ centroid,
                                                float* __restrict__ out_c,
                                                float* __restrict__ y_word) {
    const int idx = blockIdx.x * 256 + threadIdx.x;
    const int k = idx >> 11, c = idx & 2047;
    float s = 0.f;
#pragma unroll
    for (int pi = 0; pi < 32; ++pi) s += partial4[((size_t)(pi * KW + k) << 11) + c];
    int cnt = 0;
#pragma unroll
    for (int bb = 0; bb < 8; ++bb) cnt += counts[bb * KW + k];
    const float ctr = s / ((float)cnt + 1e-4f);
    out_c[idx] = 0.01f * ctr + 0.99f * centroid[idx];
    if (idx < 2048) y_word[idx] = (counts[idx] > 0) ? 1.0f : 0.0f;
}

extern "C" void kernel_launch(void* const* d_in, const int* in_sizes, int n_in,
                              void* d_out, int out_size, void* d_ws, size_t ws_size,
                              hipStream_t stream) {
    const float* x        = (const float*)d_in[0];
    const float* centroid = (const float*)d_in[1];
    float* out   = (float*)d_out;
    float* xcorr = out;                 // 8*256*4096
    float* xhist = out + 8388608;       // 2048
    float* yword = out + 8390656;       // 2048
    float* outc  = out + 8392704;       // 256*2048

    char* ws = (char*)d_ws;
    short* wt       = (short*)ws;                                   // 1 MiB (fragment layout)
    int*   labels   = (int*)(ws + (1 << 20));                       // 128 KiB
    int*   counts   = (int*)(ws + (1 << 20) + 131072);              // 8 KiB
    float* partial4 = (float*)(ws + (1 << 20) + 131072 + 8192);     // 64 MiB (32 exclusive slices)

    hipLaunchKernelGGL(k1_prep,  dim3(256),  dim3(256), 0, stream, centroid, wt, xhist, counts);
    hipLaunchKernelGGL(k2_main,  dim3(512),  dim3(256), 0, stream, x, wt, xcorr, xhist, labels, counts);
    hipLaunchKernelGGL(k3_ctr,   dim3(512),  dim3(256), 0, stream, x, labels, partial4);
    hipLaunchKernelGGL(k4_final, dim3(2048), dim3(256), 0, stream, partial4, counts, centroid, outc, yword);
}

// Round 12
// 141.429 us; speedup vs baseline: 1.6755x; 1.0949x over previous
//
#include <hip/hip_runtime.h>

typedef __attribute__((ext_vector_type(8))) short short8;
typedef __attribute__((ext_vector_type(4))) float f32x4;
typedef __attribute__((ext_vector_type(4))) unsigned int u32x4;

#define C_DIM 2048
#define KW 256
#define HW_DIM 4096

__device__ __forceinline__ short f2bf(float f) {
    unsigned u = __builtin_bit_cast(unsigned, f);
    unsigned r = (u + 0x7fffu + ((u >> 16) & 1u)) >> 16;
    return (short)r;
}

__device__ __forceinline__ float bf2f(short s) {
    return __builtin_bit_cast(float, ((unsigned)(unsigned short)s) << 16);
}

// ---------- Kernel 1: normalize centroid -> bf16 w_norm in k2's FRAGMENT layout ----------
// wt layout: [cc(32)][ks(2)][g(4)][k(256)][c8(8)], c = cc*64 + ks*32 + g*8 + c8.
__global__ __launch_bounds__(256) void k1_prep(const float* __restrict__ centroid,
                                               short* __restrict__ wt,
                                               float* __restrict__ xhist,
                                               int* __restrict__ counts) {
    const int row = blockIdx.x, t = threadIdx.x;
    const float* src = centroid + row * C_DIM;
    float v[8]; float ss = 0.f;
#pragma unroll
    for (int i = 0; i < 8; ++i) { v[i] = src[t + 256 * i]; ss += v[i] * v[i]; }
#pragma unroll
    for (int off = 1; off < 64; off <<= 1) ss += __shfl_xor(ss, off);
    __shared__ float red[4];
    if ((t & 63) == 0) red[t >> 6] = ss;
    __syncthreads();
    const float tot = red[0] + red[1] + red[2] + red[3];
    const float inv = 1.0f / fmaxf(sqrtf(tot), 1e-12f);
#pragma unroll
    for (int i = 0; i < 8; ++i) {
        const int c = t + 256 * i;
        const int idx = ((((c >> 6) * 2 + ((c >> 5) & 1)) * 4 + ((c >> 3) & 3)) * 256 + row) * 8 + (c & 7);
        wt[idx] = f2bf(v[i] * inv);
    }
    if (row == 0) {
        for (int i = t; i < 2048; i += 256) { xhist[i] = 0.f; counts[i] = 0; }
    }
}

// ---------- Kernel 2: fused GEMM, 2-phase software pipeline (raw s_barrier + counted waitcnt) ----------
__global__ __launch_bounds__(256, 2) void k2_main(const float* __restrict__ x,
                                                  const short* __restrict__ wt,
                                                  float* __restrict__ xcorr,
                                                  float* __restrict__ xhist,
                                                  int* __restrict__ labels,
                                                  int* __restrict__ counts) {
    __shared__ float sf[2][64 * 64];
    __shared__ short bfr[8 * 64 * 8];
    __shared__ float ssred[4][64];
    __shared__ float invn[64];
    __shared__ float wmax[4][64];
    __shared__ int   warg[4][64];
    __shared__ float wred[4][64];
    __shared__ float Sn[64];

    const int t = threadIdx.x;
    const int w = t >> 6, l = t & 63;
    const int p = l & 15, g = l >> 4;
    const int n0 = blockIdx.x * 64;
    const int b = n0 >> 12, hw0 = n0 & 4095;
    const float* xb = x + (size_t)b * C_DIM * HW_DIM + hw0;

    f32x4 acc[4][4];
#pragma unroll
    for (int i = 0; i < 4; ++i)
#pragma unroll
        for (int j = 0; j < 4; ++j) acc[i][j] = (f32x4)0.f;

    float ss = 0.f;
    int cur = 0;

#pragma unroll
    for (int q = 0; q < 4; ++q) {
        const int row = 4 * w + 16 * q + (l >> 4);
        const float* gsrc = xb + (size_t)row * HW_DIM + (l & 15) * 4;
        float* ldst = &sf[0][(4 * w + 16 * q) * 64];
        __builtin_amdgcn_global_load_lds(
            (const __attribute__((address_space(1))) unsigned int*)gsrc,
            (__attribute__((address_space(3))) unsigned int*)ldst, 16, 0, 0);
    }
    asm volatile("s_waitcnt vmcnt(0)" ::: "memory");
    __syncthreads();

#pragma unroll 1
    for (int cc = 0; cc < 32; ++cc) {
        const int cb = cc * 64;
        short8 af[2][4];
#pragma unroll
        for (int ks = 0; ks < 2; ++ks)
#pragma unroll
            for (int mf = 0; mf < 4; ++mf)
                af[ks][mf] = *(const short8*)(wt + (((size_t)(cc * 2 + ks) * 4 + g) * 256 + (w * 64 + mf * 16 + p)) * 8);
        __builtin_amdgcn_sched_barrier(0);
        if (cc + 1 < 32) {
#pragma unroll
            for (int q = 0; q < 4; ++q) {
                const int row = 4 * w + 16 * q + (l >> 4);
                const float* gsrc = xb + (size_t)(cb + 64 + row) * HW_DIM + (l & 15) * 4;
                float* ldst = &sf[cur ^ 1][(4 * w + 16 * q) * 64];
                __builtin_amdgcn_global_load_lds(
                    (const __attribute__((address_space(1))) unsigned int*)gsrc,
                    (__attribute__((address_space(3))) unsigned int*)ldst, 16, 0, 0);
            }
        }
        __builtin_amdgcn_sched_barrier(0);
        float tv[16];
#pragma unroll
        for (int j = 0; j < 16; ++j) {
            tv[j] = sf[cur][(16 * w + j) * 64 + l];
            ss += tv[j] * tv[j];
        }
        short8 pk0, pk1;
#pragma unroll
        for (int j = 0; j < 8; ++j) { pk0[j] = f2bf(tv[j]); pk1[j] = f2bf(tv[8 + j]); }
        *(short8*)(&bfr[((2 * w + 0) * 64 + l) * 8]) = pk0;
        *(short8*)(&bfr[((2 * w + 1) * 64 + l) * 8]) = pk1;
        asm volatile("s_waitcnt lgkmcnt(0)" ::: "memory");
        __builtin_amdgcn_sched_barrier(0);
        __builtin_amdgcn_s_barrier();
#pragma unroll
        for (int ks = 0; ks < 2; ++ks) {
            short8 bf[4];
#pragma unroll
            for (int nf = 0; nf < 4; ++nf)
                bf[nf] = *(const short8*)(&bfr[((ks * 4 + g) * 64 + nf * 16 + p) * 8]);
#pragma unroll
            for (int mf = 0; mf < 4; ++mf)
#pragma unroll
                for (int nf = 0; nf < 4; ++nf)
                    acc[mf][nf] = __builtin_amdgcn_mfma_f32_16x16x32_bf16(
                        af[ks][mf], bf[nf], acc[mf][nf], 0, 0, 0);
        }
        asm volatile("s_waitcnt vmcnt(0)" ::: "memory");
        __builtin_amdgcn_sched_barrier(0);
        __builtin_amdgcn_s_barrier();
        cur ^= 1;
    }

    // ---- epilogue ----
    ssred[w][l] = ss;
    __syncthreads();
    if (t < 64) {
        const float s = ssred[0][t] + ssred[1][t] + ssred[2][t] + ssred[3][t];
        invn[t] = 1.0f / fmaxf(sqrtf(s), 1e-12f);
    }
    __syncthreads();
    float inv[4];
#pragma unroll
    for (int nf = 0; nf < 4; ++nf) inv[nf] = invn[nf * 16 + p];

    float mx[4]; int ai[4];
#pragma unroll
    for (int nf = 0; nf < 4; ++nf) { mx[nf] = -3.0e38f; ai[nf] = 0; }
#pragma unroll
    for (int mf = 0; mf < 4; ++mf)
#pragma unroll
        for (int r = 0; r < 4; ++r) {
            const int k = w * 64 + mf * 16 + g * 4 + r;
#pragma unroll
            for (int nf = 0; nf < 4; ++nf) {
                const float v = acc[mf][nf][r] * inv[nf];
                if (v > mx[nf]) { mx[nf] = v; ai[nf] = k; }
            }
        }
#pragma unroll
    for (int off = 16; off <= 32; off <<= 1)
#pragma unroll
        for (int nf = 0; nf < 4; ++nf) {
            const float ov = __shfl_xor(mx[nf], off);
            const int   oi = __shfl_xor(ai[nf], off);
            if (ov > mx[nf] || (ov == mx[nf] && oi < ai[nf])) { mx[nf] = ov; ai[nf] = oi; }
        }
    if (l < 16) {
#pragma unroll
        for (int nf = 0; nf < 4; ++nf) { wmax[w][nf * 16 + l] = mx[nf]; warg[w][nf * 16 + l] = ai[nf]; }
    }
    __syncthreads();
    if (t < 64) {
        float m = wmax[0][t]; int a = warg[0][t];
#pragma unroll
        for (int ww = 1; ww < 4; ++ww) {
            const float om = wmax[ww][t]; const int oa = warg[ww][t];
            if (om > m || (om == m && oa < a)) { m = om; a = oa; }
        }
        labels[n0 + t] = a;
        atomicAdd(&counts[b * KW + a], 1);
    }

    float se[4] = {0.f, 0.f, 0.f, 0.f};
#pragma unroll
    for (int mf = 0; mf < 4; ++mf)
#pragma unroll
        for (int r = 0; r < 4; ++r)
#pragma unroll
            for (int nf = 0; nf < 4; ++nf)
                se[nf] += __expf(acc[mf][nf][r] * inv[nf]);
#pragma unroll
    for (int off = 16; off <= 32; off <<= 1)
#pragma unroll
        for (int nf = 0; nf < 4; ++nf) se[nf] += __shfl_xor(se[nf], off);
    if (l < 16) {
#pragma unroll
        for (int nf = 0; nf < 4; ++nf) wred[w][nf * 16 + l] = se[nf];
    }
    __syncthreads();
    if (t < 64) Sn[t] = wred[0][t] + wred[1][t] + wred[2][t] + wred[3][t];
    __syncthreads();

    float rs[4];
#pragma unroll
    for (int nf = 0; nf < 4; ++nf) rs[nf] = 1.0f / Sn[nf * 16 + p];

    float hist[4][4];
#pragma unroll
    for (int mf = 0; mf < 4; ++mf)
#pragma unroll
        for (int r = 0; r < 4; ++r) hist[mf][r] = 0.f;
#pragma unroll
    for (int mf = 0; mf < 4; ++mf)
#pragma unroll
        for (int r = 0; r < 4; ++r) {
            const int k = w * 64 + mf * 16 + g * 4 + r;
            float* orow = xcorr + ((size_t)(b * KW + k) << 12) + hw0;
#pragma unroll
            for (int nf = 0; nf < 4; ++nf) {
                const float pr = __expf(acc[mf][nf][r] * inv[nf]) * rs[nf];
                orow[nf * 16 + p] = pr;
                hist[mf][r] += pr;
            }
        }
#pragma unroll
    for (int off = 1; off <= 8; off <<= 1)
#pragma unroll
        for (int mf = 0; mf < 4; ++mf)
#pragma unroll
            for (int r = 0; r < 4; ++r) hist[mf][r] += __shfl_xor(hist[mf][r], off);
    if (p == 0) {
#pragma unroll
        for (int mf = 0; mf < 4; ++mf)
#pragma unroll
            for (int r = 0; r < 4; ++r)
                unsafeAtomicAdd(&xhist[b * KW + w * 64 + mf * 16 + g * 4 + r], hist[mf][r]);
    }
}

// ---------- Kernel 3: MFMA segmented-sum, DMA->LDS double-buffer, barrier-free counted vmcnt ----------
// grid 512 = 8 b x 4 px-groups(1024px) x 16 cc(128c). Wave owns rows [32w,32w+32): c0=..+p, c1=c0+16.
// Tile: 128c x 64px f32, XOR-swizzled at float4 granularity (slot' = slot ^ (c&15)); DMA source
// pre-swizzled, LDS dest linear (rule: both-sides-or-neither). Each wave DMAs ONLY its own rows,
// so per-wave s_waitcnt vmcnt(8) is the only sync needed (no barriers in the loop).
__global__ __launch_bounds__(256, 2) void k3_ctr(const float* __restrict__ x,
                                                 const int* __restrict__ labels,
                                                 short* __restrict__ partial4) {
    __shared__ int lab[1024];
    __shared__ float sf[2][128 * 64];   // 64 KiB
    const int t = threadIdx.x;
    const int w = t >> 6, l = t & 63;
    const int p = l & 15, g = l >> 4;
    const int cc = blockIdx.x & 15;
    const int pg = (blockIdx.x >> 4) & 3;
    const int b  = blockIdx.x >> 6;
    ((int4*)lab)[t] = ((const int4*)(labels + b * HW_DIM + pg * 1024))[t];
    __syncthreads();

    const float* xbase = x + ((size_t)b * C_DIM + cc * 128) * HW_DIM + pg * 1024;
    const int dq_row = l >> 4;          // 0..3: row within 4-row DMA chunk
    const int dq_slot = l & 15;         // float4 slot within row

    f32x4 accA[16], accB[16];
#pragma unroll
    for (int mf = 0; mf < 16; ++mf) { accA[mf] = (f32x4)0.f; accB[mf] = (f32x4)0.f; }

    const int r0 = w * 32 + p;          // chunk0 LDS row
    const int r1 = r0 + 16;             // chunk1 LDS row

    // prologue: stage tile 0 (8 DMA ops, rows [32w,32w+32))
#pragma unroll
    for (int q = 0; q < 8; ++q) {
        const int c_l = w * 32 + q * 4 + dq_row;
        const int px4 = dq_slot ^ (c_l & 15);
        const float* gsrc = xbase + (size_t)c_l * HW_DIM + px4 * 4;
        float* ldst = &sf[0][(w * 32 + q * 4) * 64];
        __builtin_amdgcn_global_load_lds(
            (const __attribute__((address_space(1))) unsigned int*)gsrc,
            (__attribute__((address_space(3))) unsigned int*)ldst, 16, 0, 0);
    }

#pragma unroll 1
    for (int it = 0; it < 16; ++it) {
        const int buf = it & 1;
        if (it + 1 < 16) {
#pragma unroll
            for (int q = 0; q < 8; ++q) {
                const int c_l = w * 32 + q * 4 + dq_row;
                const int px4 = dq_slot ^ (c_l & 15);
                const float* gsrc = xbase + (size_t)c_l * HW_DIM + (it + 1) * 64 + px4 * 4;
                float* ldst = &sf[buf ^ 1][(w * 32 + q * 4) * 64];
                __builtin_amdgcn_global_load_lds(
                    (const __attribute__((address_space(1))) unsigned int*)gsrc,
                    (__attribute__((address_space(3))) unsigned int*)ldst, 16, 0, 0);
            }
            asm volatile("s_waitcnt vmcnt(8)" ::: "memory");
        } else {
            asm volatile("s_waitcnt vmcnt(0)" ::: "memory");
        }
        __builtin_amdgcn_sched_barrier(0);
#pragma unroll
        for (int H = 0; H < 2; ++H) {
            const int sE = ((H * 8 + g * 2) ^ p) * 4;
            const int sO = ((H * 8 + g * 2 + 1) ^ p) * 4;
            const float4 v0 = *(const float4*)&sf[buf][r0 * 64 + sE];
            const float4 v1 = *(const float4*)&sf[buf][r0 * 64 + sO];
            const float4 v2 = *(const float4*)&sf[buf][r1 * 64 + sE];
            const float4 v3 = *(const float4*)&sf[buf][r1 * 64 + sO];
            short8 bfA, bfB;
            bfA[0] = f2bf(v0.x); bfA[1] = f2bf(v0.y); bfA[2] = f2bf(v0.z); bfA[3] = f2bf(v0.w);
            bfA[4] = f2bf(v1.x); bfA[5] = f2bf(v1.y); bfA[6] = f2bf(v1.z); bfA[7] = f2bf(v1.w);
            bfB[0] = f2bf(v2.x); bfB[1] = f2bf(v2.y); bfB[2] = f2bf(v2.z); bfB[3] = f2bf(v2.w);
            bfB[4] = f2bf(v3.x); bfB[5] = f2bf(v3.y); bfB[6] = f2bf(v3.z); bfB[7] = f2bf(v3.w);

            const int lb = it * 64 + H * 32 + g * 8;
            const int4 L0 = *(const int4*)&lab[lb];
            const int4 L1 = *(const int4*)&lab[lb + 4];
            const int lj[8] = {L0.x, L0.y, L0.z, L0.w, L1.x, L1.y, L1.z, L1.w};
            unsigned bits[8];
#pragma unroll
            for (int j = 0; j < 8; ++j)
                bits[j] = ((lj[j] & 15) == p) ? (1u << (lj[j] >> 4)) : 0u;
            const unsigned cmb0 = bits[0] | (bits[1] << 16);
            const unsigned cmb1 = bits[2] | (bits[3] << 16);
            const unsigned cmb2 = bits[4] | (bits[5] << 16);
            const unsigned cmb3 = bits[6] | (bits[7] << 16);

#pragma unroll
            for (int mf = 0; mf < 16; ++mf) {
                u32x4 ar;
                ar[0] = ((cmb0 >> mf) & 0x00010001u) * 0x3F80u;
                ar[1] = ((cmb1 >> mf) & 0x00010001u) * 0x3F80u;
                ar[2] = ((cmb2 >> mf) & 0x00010001u) * 0x3F80u;
                ar[3] = ((cmb3 >> mf) & 0x00010001u) * 0x3F80u;
                const short8 af = __builtin_bit_cast(short8, ar);
                accA[mf] = __builtin_amdgcn_mfma_f32_16x16x32_bf16(af, bfA, accA[mf], 0, 0, 0);
                accB[mf] = __builtin_amdgcn_mfma_f32_16x16x32_bf16(af, bfB, accB[mf], 0, 0, 0);
            }
        }
    }

    // flush: plain bf16 stores into this (b,pg)'s exclusive slice
    const int slice = b * 4 + pg;
    const int c0 = cc * 128 + w * 32 + p;
#pragma unroll
    for (int mf = 0; mf < 16; ++mf)
#pragma unroll
        for (int r = 0; r < 4; ++r) {
            const size_t rowoff = (size_t)(slice * KW + mf * 16 + g * 4 + r) << 11;
            partial4[rowoff + c0] = f2bf(accA[mf][r]);
            partial4[rowoff + c0 + 16] = f2bf(accB[mf][r]);
        }
}

// ---------- Kernel 4: reduce 32 bf16 partial slices, EMA update, y_word ----------
__global__ __launch_bounds__(256) void k4_final(const short* __restrict__ partial4,
                                                const int* __restrict__ counts,
                                                const float* __restrict__ centroid,
                                                float* __restrict__ out_c,
                                                float* __restrict__ y_word) {
    const int idx = blockIdx.x * 256 + threadIdx.x;
    const int k = idx >> 11, c = idx & 2047;
    float s = 0.f;
#pragma unroll
    for (int pi = 0; pi < 32; ++pi) s += bf2f(partial4[((size_t)(pi * KW + k) << 11) + c]);
    int cnt = 0;
#pragma unroll
    for (int bb = 0; bb < 8; ++bb) cnt += counts[bb * KW + k];
    const float ctr = s / ((float)cnt + 1e-4f);
    out_c[idx] = 0.01f * ctr + 0.99f * centroid[idx];
    if (idx < 2048) y_word[idx] = (counts[idx] > 0) ? 1.0f : 0.0f;
}

extern "C" void kernel_launch(void* const* d_in, const int* in_sizes, int n_in,
                              void* d_out, int out_size, void* d_ws, size_t ws_size,
                              hipStream_t stream) {
    const float* x        = (const float*)d_in[0];
    const float* centroid = (const float*)d_in[1];
    float* out   = (float*)d_out;
    float* xcorr = out;                 // 8*256*4096
    float* xhist = out + 8388608;       // 2048
    float* yword = out + 8390656;       // 2048
    float* outc  = out + 8392704;       // 256*2048

    char* ws = (char*)d_ws;
    short* wt       = (short*)ws;                                   // 1 MiB (fragment layout)
    int*   labels   = (int*)(ws + (1 << 20));                       // 128 KiB
    int*   counts   = (int*)(ws + (1 << 20) + 131072);              // 8 KiB
    short* partial4 = (short*)(ws + (1 << 20) + 131072 + 8192);     // 32 MiB (32 exclusive bf16 slices)

    hipLaunchKernelGGL(k1_prep,  dim3(256),  dim3(256), 0, stream, centroid, wt, xhist, counts);
    hipLaunchKernelGGL(k2_main,  dim3(512),  dim3(256), 0, stream, x, wt, xcorr, xhist, labels, counts);
    hipLaunchKernelGGL(k3_ctr,   dim3(512),  dim3(256), 0, stream, x, labels, partial4);
    hipLaunchKernelGGL(k4_final, dim3(2048), dim3(256), 0, stream, partial4, counts, centroid, outc, yword);
}